// Round 4
// baseline (148.976 us; speedup 1.0000x reference)
//
#include <hip/hip_runtime.h>

#define NSZ   192
#define NSZ2  (NSZ*NSZ)
#define NSZ3  (NSZ*NSZ*NSZ)
#define N1    191
#define TW    64
#define TH    16
#define TD    8
#define LROWS 19              // value rows h0-1 .. h0+17
#define PADW  72              // LDS row floats; LDS col c <-> global col w0-4+c
#define ROWF4 18
#define SLOTF4R 1026          // real float4 per slot (3ch * 19 rows * 18)
#define SLOTF4P 1088          // padded: full-wave chunk-4 overrun lands in pad
#define SLOTF  (SLOTF4P*4)    // 4352 floats per slot
#define NTHREADS 256

__device__ __forceinline__ void gload_lds16(const float* g, float* l) {
    __builtin_amdgcn_global_load_lds((const __attribute__((address_space(1))) void*)g,
                                     (__attribute__((address_space(3))) void*)l, 16, 0, 0);
}

__device__ __forceinline__ void ld8(float* d, const float* p) {
    *(float2*)&d[0] = *(const float2*)&p[0];
    *(float2*)&d[2] = *(const float2*)&p[2];
    *(float2*)&d[4] = *(const float2*)&p[4];
    *(float2*)&d[6] = *(const float2*)&p[6];
}

// stage one y-slice (3ch x 19 rows x 72 cols, clamped) into an LDS slot,
// fully via async global->LDS DMA. LDS f4 index == tid + k*256 (linear).
__device__ __forceinline__ void stage(const float* __restrict__ y, float* slot,
                                      int s, const int* goff, int tid) {
    const float* src = y + (size_t)s * NSZ2;
    gload_lds16(src + goff[0], slot + (size_t)tid * 4);
    gload_lds16(src + goff[1], slot + (size_t)(tid + 256) * 4);
    gload_lds16(src + goff[2], slot + (size_t)(tid + 512) * 4);
    gload_lds16(src + goff[3], slot + (size_t)(tid + 768) * 4);
    if (tid < 64)  // full wave 0; lanes past 1026 write the slot pad (clamped src)
        gload_lds16(src + goff[4], slot + (size_t)(1024 + tid) * 4);
}

#define IDX(c,dir,q) (((c)*3+(dir))*4+(q))

__global__ __launch_bounds__(NTHREADS, 3)
void jac_kernel(const float* __restrict__ y, float* __restrict__ out) {
    __shared__ __align__(16) float lds[3 * SLOTF];

    const int tx = threadIdx.x;          // 0..15, owns 4 output cols
    const int ty = threadIdx.y;          // 0..15, owns 1 output row
    const int tid = ty * 16 + tx;
    const int w0 = blockIdx.x * TW;
    const int h0 = blockIdx.y * TH;
    const int d0 = blockIdx.z * TD;
    const int j  = h0 + ty;
    const int k0 = w0 + 4 * tx;

    // validity masks: filter cols gk = k0-1+p (p=0..5), rows gr = j-1+r
    float colv[6], rowv[3];
    #pragma unroll
    for (int p = 0; p < 6; ++p) {
        int gk = k0 - 1 + p;
        colv[p] = (gk >= 0 && gk < N1) ? 1.f : 0.f;
    }
    #pragma unroll
    for (int r = 0; r < 3; ++r) {
        int gr = j - 1 + r;
        rowv[r] = (gr >= 0 && gr < N1) ? 1.f : 0.f;
    }

    // staging source offsets (slice-invariant part), computed once
    int goff[5];
    #pragma unroll
    for (int k = 0; k < 5; ++k) {
        int e4 = (k < 4) ? (tid + k * 256) : (1024 + (tid & 63));
        if (e4 > SLOTF4R - 1) e4 = SLOTF4R - 1;     // clamp pad lanes
        int rowidx = e4 / ROWF4;
        int m   = e4 - rowidx * ROWF4;
        int ch  = rowidx / LROWS;
        int row = rowidx - ch * LROWS;
        int gr = h0 - 1 + row; gr = gr < 0 ? 0 : (gr > N1 ? N1 : gr);
        int c4 = w0 - 4 + 4 * m; c4 = c4 < 0 ? 0 : (c4 > NSZ - 4 ? NSZ - 4 : c4);
        goff[k] = ch * NSZ3 + gr * NSZ + c4;
    }

    // d-direction ring: a1 = acc(i-1), a2 = acc(i-2); f(i-1) = a2+a1+acc(i)
    float a1[36], a2[36];
    #pragma unroll
    for (int t = 0; t < 36; ++t) { a1[t] = 0.f; a2[t] = 0.f; }

    // prologue: stage slices d0-1 (if exists) and d0
    if (d0 >= 1) stage(y, lds + ((d0 + 2) % 3) * SLOTF, d0 - 1, goff, tid);
    stage(y, lds + (d0 % 3) * SLOTF, d0, goff, tid);
    __syncthreads();

    int sA = (d0 + 2) % 3;               // slot of slice i = d0-1
    const int wbase = 4 * tx + 2;        // window float offset within row

    for (int ii = 0; ii < TD + 2; ++ii) {
        const int i  = d0 - 1 + ii;
        const int sB = sA == 2 ? 0 : sA + 1;
        const int sC = sB == 2 ? 0 : sB + 1;

        // issue async staging of slice i+2 into sC (in flight across compute)
        if (ii <= TD && i + 2 <= N1)
            stage(y, lds + sC * SLOTF, i + 2, goff, tid);

        float f[36];

        if (i >= 0 && i < N1) {          // uniform: diff slice i exists
            #pragma unroll
            for (int c = 0; c < 3; ++c) {
                const float* pA = lds + sA * SLOTF + (c * LROWS + ty) * PADW + wbase;
                const float* pB = lds + sB * SLOTF + (c * LROWS + ty) * PADW + wbase;
                float acc[12];
                float Y0[8], Y1[8], Z0[8];
                ld8(Y0, pA);                       // value row j-1 @ slice i
                #pragma unroll
                for (int r = 0; r < 3; ++r) {      // filter rows gr = j-1+r
                    ld8(Y1, pA + (r + 1) * PADW);  // value row gr+1 @ slice i
                    ld8(Z0, pB + r * PADW);        // value row gr   @ slice i+1
                    const float rv = rowv[r];
                    float dH[6], dD[6], dW[6];
                    #pragma unroll
                    for (int p = 0; p < 6; ++p) {
                        const float cm = colv[p];
                        dH[p] = fabsf(Y1[p + 1] - Y0[p + 1]) * cm;
                        dD[p] = fabsf(Z0[p + 1] - Y0[p + 1]) * cm;
                        dW[p] = fabsf(Y0[p + 2] - Y0[p + 1]) * cm;
                    }
                    // w-box sums (shared pairs) + h accumulation via fmac
                    {
                        float e12 = dH[1] + dH[2], e34 = dH[3] + dH[4];
                        float t0 = dH[0] + e12, t1 = e12 + dH[3];
                        float t2 = dH[2] + e34, t3 = e34 + dH[5];
                        if (r == 0) { acc[0] = rv * t0; acc[1] = rv * t1; acc[2] = rv * t2; acc[3] = rv * t3; }
                        else { acc[0] = fmaf(rv, t0, acc[0]); acc[1] = fmaf(rv, t1, acc[1]);
                               acc[2] = fmaf(rv, t2, acc[2]); acc[3] = fmaf(rv, t3, acc[3]); }
                    }
                    {
                        float e12 = dD[1] + dD[2], e34 = dD[3] + dD[4];
                        float t0 = dD[0] + e12, t1 = e12 + dD[3];
                        float t2 = dD[2] + e34, t3 = e34 + dD[5];
                        if (r == 0) { acc[4] = rv * t0; acc[5] = rv * t1; acc[6] = rv * t2; acc[7] = rv * t3; }
                        else { acc[4] = fmaf(rv, t0, acc[4]); acc[5] = fmaf(rv, t1, acc[5]);
                               acc[6] = fmaf(rv, t2, acc[6]); acc[7] = fmaf(rv, t3, acc[7]); }
                    }
                    {
                        float e12 = dW[1] + dW[2], e34 = dW[3] + dW[4];
                        float t0 = dW[0] + e12, t1 = e12 + dW[3];
                        float t2 = dW[2] + e34, t3 = e34 + dW[5];
                        if (r == 0) { acc[8] = rv * t0; acc[9] = rv * t1; acc[10] = rv * t2; acc[11] = rv * t3; }
                        else { acc[8] = fmaf(rv, t0, acc[8]); acc[9] = fmaf(rv, t1, acc[9]);
                               acc[10] = fmaf(rv, t2, acc[10]); acc[11] = fmaf(rv, t3, acc[11]); }
                    }
                    #pragma unroll
                    for (int p = 0; p < 8; ++p) Y0[p] = Y1[p];
                }
                // fold into d-ring (per channel)
                #pragma unroll
                for (int t = 0; t < 12; ++t) {
                    const int gi = c * 12 + t;
                    f[gi]  = a2[gi] + a1[gi] + acc[t];
                    a2[gi] = a1[gi];
                    a1[gi] = acc[t];
                }
            }
        } else {                         // acc == 0: rotate ring with zeros
            #pragma unroll
            for (int t = 0; t < 36; ++t) {
                f[t]  = a2[t] + a1[t];
                a2[t] = a1[t];
                a1[t] = 0.f;
            }
        }

        const int d = i - 1;
        if (ii >= 2 && d < N1 && j < N1) {
            const float K = 27.f, KS = 1.f / 19683.f;   // det scaled by 27^3
            #pragma unroll
            for (int q = 0; q < 4; ++q) {
                if (k0 + q < N1) {
                    float ayx = f[IDX(0,0,q)], ayy = f[IDX(0,1,q)], ayz = f[IDX(0,2,q)];
                    float axx = f[IDX(1,0,q)], axy = f[IDX(1,1,q)], axz = f[IDX(1,2,q)];
                    float azx = f[IDX(2,0,q)], azy = f[IDX(2,1,q)], azz = f[IDX(2,2,q)];
                    float ayy27 = ayy + K, azz27 = azz + K, axx27 = axx + K;
                    float t = fmaf(-ayz, azy, ayy27 * azz27);
                    float v = fmaf(-ayz, azx, ayx * azz27);
                    float w = fmaf(-ayy27, azx, ayx * azy);
                    float R = axx27 * t;
                    R = fmaf(-axy, v, R);
                    R = fmaf(axz, w, R);
                    out[(d * N1 + j) * N1 + (k0 + q)] = R * KS;
                }
            }
        }

        __syncthreads();                 // drains vmcnt: staged slice i+2 ready
        sA = sB;
    }
}

extern "C" void kernel_launch(void* const* d_in, const int* in_sizes, int n_in,
                              void* d_out, int out_size, void* d_ws, size_t ws_size,
                              hipStream_t stream) {
    const float* y = (const float*)d_in[0];
    float* out = (float*)d_out;
    dim3 grid(3, 12, 24);     // w-tiles, h-tiles, d-chunks
    dim3 block(16, 16, 1);
    jac_kernel<<<grid, block, 0, stream>>>(y, out);
}

// Round 5
// 103.408 us; speedup vs baseline: 1.4407x; 1.4407x over previous
//
#include <hip/hip_runtime.h>

#define NSZ   192
#define NSZ2  (NSZ*NSZ)
#define NSZ3  (NSZ*NSZ*NSZ)
#define N1    191
#define TW    64
#define TH    16
#define TD    8
#define LROWS 19              // value rows h0-1 .. h0+17 (row-clamped => replicated)
#define PADW  72              // LDS row floats; LDS col c <-> global col w0-4+c
#define ROWF4 18
#define SLOTF4R 1026          // real float4 per slot (3ch * 19 rows * 18)
#define SLOTF4P 1088          // padded: full-wave chunk-4 overrun lands in pad
#define SLOTF  (SLOTF4P*4)    // 4352 floats per slot
#define NTHREADS 256

__device__ __forceinline__ void gload_lds16(const float* g, float* l) {
    __builtin_amdgcn_global_load_lds((const __attribute__((address_space(1))) void*)g,
                                     (__attribute__((address_space(3))) void*)l, 16, 0, 0);
}

__device__ __forceinline__ void ld8(float* d, const float* p) {
    *(float2*)&d[0] = *(const float2*)&p[0];
    *(float2*)&d[2] = *(const float2*)&p[2];
    *(float2*)&d[4] = *(const float2*)&p[4];
    *(float2*)&d[6] = *(const float2*)&p[6];
}

// stage one y-slice (3ch x 19 rows x 72 cols, clamped) into an LDS slot via
// async global->LDS DMA. LDS f4 index == tid + k*256 (linear, DMA contract).
__device__ __forceinline__ void stage(const float* __restrict__ y, float* slot,
                                      int s, const int* goff, int tid) {
    const float* src = y + (size_t)s * NSZ2;
    gload_lds16(src + goff[0], slot + (size_t)tid * 4);
    gload_lds16(src + goff[1], slot + (size_t)(tid + 256) * 4);
    gload_lds16(src + goff[2], slot + (size_t)(tid + 512) * 4);
    gload_lds16(src + goff[3], slot + (size_t)(tid + 768) * 4);
    if (tid < 64)  // full wave 0; lanes past 1026 write the slot pad (clamped src)
        gload_lds16(src + goff[4], slot + (size_t)(1024 + tid) * 4);
}

#define IDX(c,dir,q) (((c)*3+(dir))*4+(q))

// box-sum of 4 sliding windows over 6 masked |diff| values, shared-pair FMA form
#define WSUM_MASKED(d, t0, t1, t2, t3)                              \
    {   float e12 = fmaf(colv[2], fabsf(d[2]), colv[1] * fabsf(d[1])); \
        float e34 = fmaf(colv[4], fabsf(d[4]), colv[3] * fabsf(d[3])); \
        t0 = fmaf(colv[0], fabsf(d[0]), e12);                       \
        t1 = fmaf(colv[3], fabsf(d[3]), e12);                       \
        t2 = fmaf(colv[2], fabsf(d[2]), e34);                       \
        t3 = fmaf(colv[5], fabsf(d[5]), e34); }

__global__ __launch_bounds__(NTHREADS, 2)
void jac_kernel(const float* __restrict__ y, float* __restrict__ out) {
    __shared__ __align__(16) float lds[3 * SLOTF];

    const int tx = threadIdx.x;          // 0..15, owns 4 output cols
    const int ty = threadIdx.y;          // 0..15, owns 1 output row
    const int tid = ty * 16 + tx;
    const int w0 = blockIdx.x * TW;
    const int h0 = blockIdx.y * TH;
    const int d0 = blockIdx.z * TD;
    const int j  = h0 + ty;
    const int k0 = w0 + 4 * tx;

    // validity masks: filter cols gk = k0-1+p (p=0..5), filter rows gr = j-1+r
    float colv[6], rowv[3];
    #pragma unroll
    for (int p = 0; p < 6; ++p) {
        int gk = k0 - 1 + p;
        colv[p] = (gk >= 0 && gk < N1) ? 1.f : 0.f;
    }
    #pragma unroll
    for (int r = 0; r < 3; ++r) {
        int gr = j - 1 + r;
        rowv[r] = (gr >= 0 && gr < N1) ? 1.f : 0.f;
    }

    // staging source offsets (slice-invariant), computed once
    int goff[5];
    #pragma unroll
    for (int k = 0; k < 5; ++k) {
        int e4 = (k < 4) ? (tid + k * 256) : (1024 + (tid & 63));
        if (e4 > SLOTF4R - 1) e4 = SLOTF4R - 1;
        int rowidx = e4 / ROWF4;
        int m   = e4 - rowidx * ROWF4;
        int ch  = rowidx / LROWS;
        int row = rowidx - ch * LROWS;
        int gr = h0 - 1 + row; gr = gr < 0 ? 0 : (gr > N1 ? N1 : gr);
        int c4 = w0 - 4 + 4 * m; c4 = c4 < 0 ? 0 : (c4 > NSZ - 4 ? NSZ - 4 : c4);
        goff[k] = ch * NSZ3 + gr * NSZ + c4;
    }

    // d-ring (pair-sum form): a1 = acc(i-1), b = acc(i-1)+acc(i-2)
    // f(i-1) = b + acc(i);  b' = a1 + acc(i);  a1' = acc(i)
    float a1[36], b[36];
    #pragma unroll
    for (int t = 0; t < 36; ++t) { a1[t] = 0.f; b[t] = 0.f; }

    // prologue: stage slices d0-1 (if exists) and d0
    if (d0 >= 1) stage(y, lds + ((d0 + 2) % 3) * SLOTF, d0 - 1, goff, tid);
    stage(y, lds + (d0 % 3) * SLOTF, d0, goff, tid);
    __syncthreads();

    int sA = (d0 + 2) % 3;               // slot of slice i = d0-1
    const int wbase = 4 * tx + 2;        // window float offset within row

    for (int ii = 0; ii < TD + 2; ++ii) {
        const int i  = d0 - 1 + ii;
        const int sB = sA == 2 ? 0 : sA + 1;
        const int sC = sB == 2 ? 0 : sB + 1;

        // issue async staging of slice i+2 into sC (in flight across compute)
        if (ii <= TD && i + 2 <= N1)
            stage(y, lds + sC * SLOTF, i + 2, goff, tid);

        float f[36];

        if (i >= 0 && i < N1) {          // uniform: diff slice i exists
            #pragma unroll
            for (int c = 0; c < 3; ++c) {
                const float* pA = lds + sA * SLOTF + (c * LROWS + ty) * PADW + wbase;
                const float* pB = lds + sB * SLOTF + (c * LROWS + ty) * PADW + wbase;
                float acc[12];
                float Y0[8], Y1[8], Z0[8];
                ld8(Y0, pA);                       // value row j-1 @ slice i
                #pragma unroll
                for (int r = 0; r < 3; ++r) {      // filter rows gr = j-1+r
                    ld8(Y1, pA + (r + 1) * PADW);  // value row gr+1 @ slice i
                    ld8(Z0, pB + r * PADW);        // value row gr   @ slice i+1
                    const float rv = rowv[r];
                    float dH[6], dD[6], dW[6];
                    #pragma unroll
                    for (int p = 0; p < 6; ++p) {
                        dH[p] = Y1[p + 1] - Y0[p + 1];
                        dD[p] = Z0[p + 1] - Y0[p + 1];
                        dW[p] = Y0[p + 2] - Y0[p + 1];
                    }
                    float h0s, h1s, h2s, h3s, d0s, d1s, d2s, d3s, w0s, w1s, w2s, w3s;
                    WSUM_MASKED(dH, h0s, h1s, h2s, h3s)   // row-mask not needed (row clamp)
                    WSUM_MASKED(dD, d0s, d1s, d2s, d3s)   // needs rv too
                    WSUM_MASKED(dW, w0s, w1s, w2s, w3s)   // needs rv too (left-halo garbage masked by colv)
                    if (r == 0) {
                        acc[0] = h0s;      acc[1] = h1s;      acc[2] = h2s;      acc[3] = h3s;
                        acc[4] = rv * d0s; acc[5] = rv * d1s; acc[6] = rv * d2s; acc[7] = rv * d3s;
                        acc[8] = rv * w0s; acc[9] = rv * w1s; acc[10] = rv * w2s; acc[11] = rv * w3s;
                    } else {
                        acc[0] += h0s; acc[1] += h1s; acc[2] += h2s; acc[3] += h3s;
                        acc[4] = fmaf(rv, d0s, acc[4]); acc[5] = fmaf(rv, d1s, acc[5]);
                        acc[6] = fmaf(rv, d2s, acc[6]); acc[7] = fmaf(rv, d3s, acc[7]);
                        acc[8] = fmaf(rv, w0s, acc[8]); acc[9] = fmaf(rv, w1s, acc[9]);
                        acc[10] = fmaf(rv, w2s, acc[10]); acc[11] = fmaf(rv, w3s, acc[11]);
                    }
                    #pragma unroll
                    for (int p = 0; p < 8; ++p) Y0[p] = Y1[p];
                }
                // fold into d-ring (per channel)
                #pragma unroll
                for (int t = 0; t < 12; ++t) {
                    const int gi = c * 12 + t;
                    const float ac = acc[t];
                    f[gi]  = b[gi] + ac;
                    b[gi]  = a1[gi] + ac;
                    a1[gi] = ac;
                }
            }
        } else {                         // acc == 0: rotate ring with zeros
            #pragma unroll
            for (int t = 0; t < 36; ++t) {
                f[t]  = b[t];
                b[t]  = a1[t];
                a1[t] = 0.f;
            }
        }

        const int d = i - 1;
        if (ii >= 2 && d < N1 && j < N1) {
            const float K = 27.f, KS = 1.f / 19683.f;   // det scaled by 27^3
            #pragma unroll
            for (int q = 0; q < 4; ++q) {
                if (k0 + q < N1) {
                    float ayx = f[IDX(0,0,q)], ayy = f[IDX(0,1,q)], ayz = f[IDX(0,2,q)];
                    float axx = f[IDX(1,0,q)], axy = f[IDX(1,1,q)], axz = f[IDX(1,2,q)];
                    float azx = f[IDX(2,0,q)], azy = f[IDX(2,1,q)], azz = f[IDX(2,2,q)];
                    float ayy27 = ayy + K, azz27 = azz + K, axx27 = axx + K;
                    float t = fmaf(-ayz, azy, ayy27 * azz27);
                    float v = fmaf(-ayz, azx, ayx * azz27);
                    float w = fmaf(-ayy27, azx, ayx * azy);
                    float R = axx27 * t;
                    R = fmaf(-axy, v, R);
                    R = fmaf(axz, w, R);
                    out[(d * N1 + j) * N1 + (k0 + q)] = R * KS;
                }
            }
        }

        __syncthreads();                 // drains vmcnt: staged slice i+2 ready
        sA = sB;
    }
}

extern "C" void kernel_launch(void* const* d_in, const int* in_sizes, int n_in,
                              void* d_out, int out_size, void* d_ws, size_t ws_size,
                              hipStream_t stream) {
    const float* y = (const float*)d_in[0];
    float* out = (float*)d_out;
    dim3 grid(3, 12, 24);     // w-tiles, h-tiles, d-chunks
    dim3 block(16, 16, 1);
    jac_kernel<<<grid, block, 0, stream>>>(y, out);
}